// Round 4
// baseline (69184.973 us; speedup 1.0000x reference)
//
#include <hip/hip_runtime.h>
#include <cstdint>
#include <cstddef>

// B=256, P=196, C=512, D=512, A=256, E=256, V=193, TC=256, T=255

typedef unsigned short u16;
typedef unsigned int u32;
typedef __attribute__((ext_vector_type(8))) short short8;
typedef __attribute__((ext_vector_type(4))) float f32x4;

__device__ __forceinline__ float sigf(float x){ return 1.f/(1.f+expf(-x)); }
__device__ __forceinline__ u16 f2bf(float f){
  u32 u = __builtin_bit_cast(u32, f);
  u32 r = (u + 0x7fffu + ((u>>16)&1u)) >> 16;
  return (u16)r;
}
__device__ __forceinline__ float bf2f(u16 u){
  u32 x = ((u32)u) << 16;
  return __builtin_bit_cast(float, x);
}

// ---------------- zero preds/alphas + barrier state ----------------
__global__ void k_zero(float* a, int na4, float* b, int nb4, int* bar){
  int i = blockIdx.x*blockDim.x + threadIdx.x;
  int stride = gridDim.x*blockDim.x;
  float4 z = make_float4(0.f,0.f,0.f,0.f);
  for (int j = i; j < na4; j += stride) ((float4*)a)[j] = z;
  for (int j = i; j < nb4; j += stride) ((float4*)b)[j] = z;
  if (blockIdx.x == 0 && threadIdx.x < 32) bar[threadIdx.x] = 0;
}

// ---------------- sort (stable descending by length) ----------------
__global__ void k_sort(const int* cap_lens, int* si, int* dlw, float* out_dl, float* out_si){
  __shared__ int lens[256];
  int tid = threadIdx.x;
  lens[tid] = cap_lens[tid];
  __syncthreads();
  int L = lens[tid];
  int rank = 0;
  for (int j = 0; j < 256; ++j){
    int Lj = lens[j];
    rank += ((Lj > L) || (Lj == L && j < tid)) ? 1 : 0;
  }
  si[rank] = tid;
  dlw[rank] = L - 1;
  out_dl[rank] = (float)(L - 1);
  out_si[rank] = (float)tid;
}

// ---------------- caps gather ----------------
__global__ void k_caps(const int* caps, const int* si, int* caps_s, float* out_caps){
  int b = blockIdx.x, t = threadIdx.x;
  int v = caps[si[b]*256 + t];
  caps_s[b*256 + t] = v;
  out_caps[b*256 + t] = (float)v;
}

// ---------------- gather+convert encoder rows to bf16 (sorted order) ----------------
__global__ void k_prep(const float* enc, const int* si, u16* enc_sb){
  int b = blockIdx.x, tid = threadIdx.x;
  const float* src = enc + (size_t)si[b]*100352;
  u16* dst = enc_sb + (size_t)b*100352;
  for (int i = tid; i < 25088; i += 256){
    float4 v = *(const float4*)&src[i*4];
    ushort4 o;
    o.x = f2bf(v.x); o.y = f2bf(v.y); o.z = f2bf(v.z); o.w = f2bf(v.w);
    *(ushort4*)&dst[i*4] = o;
  }
}

// ---------------- mean of encoder rows ----------------
__global__ void k_mean(const float* enc, const int* si, u16* mean_bf){
  int b = blockIdx.x, tid = threadIdx.x;
  const float* eb = enc + (size_t)si[b]*100352;
  int cc = 2*tid;
  float s0 = 0.f, s1 = 0.f;
  #pragma unroll 4
  for (int pp = 0; pp < 196; ++pp){
    float2 v = *(const float2*)&eb[(size_t)pp*512 + cc];
    s0 += v.x; s1 += v.y;
  }
  mean_bf[b*512 + cc]     = f2bf(s0 * (1.f/196.f));
  mean_bf[b*512 + cc + 1] = f2bf(s1 * (1.f/196.f));
}

// ---------------- weight concat + bf16 convert ----------------
struct ConcatP {
  const float *Wdec,*bdec,*Wfb,*bfb,*Wfc,*bfc,*Wih,*bih,*Whh,*bhh,*Winh,*binh,*Winc,*binc,*Wenc,*emb;
  u16 *Wc0,*Wc1,*Wc3,*Wenc_bf,*emb_bf;
  float *bc0,*bc1,*bc3;
};
__global__ void k_concat(ConcatP p){
  int idx = blockIdx.x*blockDim.x + threadIdx.x;
  int stride = gridDim.x*blockDim.x;
  for (int i = idx; i < 1024*512; i += stride){
    int n = i >> 9, k = i & 511;
    float v = (n < 512) ? p.Winh[n*512 + k] : p.Winc[(n-512)*512 + k];
    p.Wc0[i] = f2bf(v);
  }
  for (int i = idx; i < 1024; i += stride)
    p.bc0[i] = (i < 512) ? p.binh[i] : p.binc[i-512];
  for (int i = idx; i < 1024*512; i += stride){
    int n = i >> 9, k = i & 511;
    float v = (n < 256) ? p.Wdec[n*512+k]
            : (n < 768) ? p.Wfb[(n-256)*512+k]
            : (n < 961) ? p.Wfc[(n-768)*512+k] : 0.f;
    p.Wc1[i] = f2bf(v);
  }
  for (int i = idx; i < 1024; i += stride)
    p.bc1[i] = (i < 256) ? p.bdec[i] : (i < 768) ? p.bfb[i-256] : (i < 961) ? p.bfc[i-768] : 0.f;
  // Wc3: gate-interleaved [W_ih | W_hh] (2048 x 1280), row n'=4*j+g -> orig row g*512+j
  for (int i = idx; i < 2048*1280; i += stride){
    int n = i / 1280, k = i - n*1280;
    int j = n >> 2, g = n & 3, orow = g*512 + j;
    float v = (k < 768) ? p.Wih[orow*768 + k] : p.Whh[orow*512 + (k - 768)];
    p.Wc3[i] = f2bf(v);
  }
  for (int i = idx; i < 2048; i += stride){
    int j = i >> 2, g = i & 3, orow = g*512 + j;
    p.bc3[i] = p.bih[orow] + p.bhh[orow];
  }
  for (int i = idx; i < 256*512; i += stride) p.Wenc_bf[i] = f2bf(p.Wenc[i]);
  for (int i = idx; i < 193*256; i += stride) p.emb_bf[i] = f2bf(p.emb[i]);
}

// ---------------- setup MFMA GEMM (double-buffered), used for init + enc_att ----------------
struct MfmaP {
  const u16* A; const u16* Bw; const float* bias;
  int K, N;
  u16* out_bf;
  u16* h_bf; float* c;
};

template<int MODE, int NT>
__global__ __launch_bounds__(256) void k_mfma(MfmaP p){
  __shared__ __align__(16) unsigned char smem[16384 + 16384*NT];
  u16* As0 = (u16*)smem;
  u16* Bs0 = (u16*)(smem + 16384);

  const int tid  = threadIdx.x;
  const int bn0  = blockIdx.x * 64 * NT;
  const int bm0  = blockIdx.y * 64;
  const int wave = tid >> 6;
  const int lane = tid & 63;
  const int ln   = lane & 15;
  const int quad = lane >> 4;

  f32x4 acc[4][NT] = {};
  short8 pa[2], pb[2*NT];

  const int srow = tid >> 3;
  const int sgc  = tid & 7;

  #pragma unroll
  for (int r = 0; r < 2; ++r)
    pa[r] = *(const short8*)(p.A + (size_t)(bm0 + srow + 32*r)*p.K + sgc*8);
  #pragma unroll
  for (int r = 0; r < 2*NT; ++r)
    pb[r] = *(const short8*)(p.Bw + (size_t)(bn0 + srow + 32*r)*p.K + sgc*8);
  #pragma unroll
  for (int r = 0; r < 2; ++r){
    int row = srow + 32*r;
    *(short8*)&As0[row*64 + ((sgc ^ (row & 7))<<3)] = pa[r];
  }
  #pragma unroll
  for (int r = 0; r < 2*NT; ++r){
    int row = srow + 32*r;
    *(short8*)&Bs0[row*64 + ((sgc ^ (row & 7))<<3)] = pb[r];
  }

  const int nIter = p.K >> 6;
  int ib = 0;
  for (int it = 0; ; ){
    __syncthreads();
    const bool more = (it + 1 < nIter);
    if (more){
      int k0 = (it + 1) << 6;
      #pragma unroll
      for (int r = 0; r < 2; ++r)
        pa[r] = *(const short8*)(p.A + (size_t)(bm0 + srow + 32*r)*p.K + k0 + sgc*8);
      #pragma unroll
      for (int r = 0; r < 2*NT; ++r)
        pb[r] = *(const short8*)(p.Bw + (size_t)(bn0 + srow + 32*r)*p.K + k0 + sgc*8);
    }
    const u16* As = &As0[ib*4096];
    const u16* Bs = &Bs0[ib*4096*NT];
    #pragma unroll
    for (int kk = 0; kk < 2; ++kk){
      short8 af[4], bfr[NT];
      #pragma unroll
      for (int mt = 0; mt < 4; ++mt){
        int row = mt*16 + ln;
        int g = kk*4 + quad;
        af[mt] = *(const short8*)&As[row*64 + ((g ^ (row & 7))<<3)];
      }
      #pragma unroll
      for (int nt = 0; nt < NT; ++nt){
        int row = (wave*NT + nt)*16 + ln;
        int g = kk*4 + quad;
        bfr[nt] = *(const short8*)&Bs[row*64 + ((g ^ (row & 7))<<3)];
      }
      #pragma unroll
      for (int mt = 0; mt < 4; ++mt)
        #pragma unroll
        for (int nt = 0; nt < NT; ++nt)
          acc[mt][nt] = __builtin_amdgcn_mfma_f32_16x16x32_bf16(af[mt], bfr[nt], acc[mt][nt], 0, 0, 0);
    }
    if (!more) break;
    ib ^= 1;
    u16* Aw = &As0[ib*4096];
    u16* Bww = &Bs0[ib*4096*NT];
    #pragma unroll
    for (int r = 0; r < 2; ++r){
      int row = srow + 32*r;
      *(short8*)&Aw[row*64 + ((sgc ^ (row & 7))<<3)] = pa[r];
    }
    #pragma unroll
    for (int r = 0; r < 2*NT; ++r){
      int row = srow + 32*r;
      *(short8*)&Bww[row*64 + ((sgc ^ (row & 7))<<3)] = pb[r];
    }
    ++it;
  }

  #pragma unroll
  for (int nt = 0; nt < NT; ++nt){
    int n = bn0 + (wave*NT + nt)*16 + ln;
    float bv = p.bias[n];
    #pragma unroll
    for (int mt = 0; mt < 4; ++mt)
      #pragma unroll
      for (int r = 0; r < 4; ++r){
        int m = bm0 + mt*16 + quad*4 + r;
        float v = acc[mt][nt][r] + bv;
        if (MODE == 0){
          p.out_bf[(size_t)m*p.N + n] = f2bf(v);
        } else { // MODE 1
          if (n < 512) p.h_bf[m*512 + n] = f2bf(v);
          else         p.c[m*512 + n - 512] = v;
        }
      }
  }
}

// ---------------- two-level grid barrier (monotone epochs, agent scope) ----------------
__device__ __forceinline__ void gridbar(int* bar, int ep, int blk){
  __threadfence();
  __syncthreads();
  if (threadIdx.x == 0){
    int g = blk & 15;
    int v = __hip_atomic_fetch_add(&bar[g], 1, __ATOMIC_ACQ_REL, __HIP_MEMORY_SCOPE_AGENT);
    if ((v & 15) == 15){
      int r = __hip_atomic_fetch_add(&bar[16], 1, __ATOMIC_ACQ_REL, __HIP_MEMORY_SCOPE_AGENT);
      if ((r & 15) == 15)
        __hip_atomic_store(&bar[17], ep + 1, __ATOMIC_RELEASE, __HIP_MEMORY_SCOPE_AGENT);
    }
    while (__hip_atomic_load(&bar[17], __ATOMIC_ACQUIRE, __HIP_MEMORY_SCOPE_AGENT) <= ep)
      __builtin_amdgcn_s_sleep(1);
  }
  __syncthreads();
  __threadfence();
}

// ---------------- persistent step kernel: 256 blocks x 256 threads, 1 block/CU ----------------
// LDS: Wc1 slice (16x520 bf16) + Wc3 slice (32x1288 bf16) persistent; scratch overlay.
struct StepP {
  const u16 *Wc1, *Wc3;
  const float *bc1, *bc3;
  const u16 *enc_att, *enc_sb, *emb_bf;
  const float *wfull, *bfull;
  const int *caps_s, *dl;
  u16 *h_bf, *z_bf;
  float *c, *dec_att, *gatev, *preds, *alphas;
  int* bar;
};

__global__ __launch_bounds__(256) void k_step(StepP p){
  __shared__ __align__(16) unsigned char smem[110592];
  u16* W1s = (u16*)smem;                    // 16 x 520 bf16  (16640 B)
  u16* W3s = (u16*)(smem + 16640);          // 32 x 1288 bf16 (82432 B) -> ends 99072
  float* scr = (float*)(smem + 99072);      // 11520 B scratch

  const int tid  = threadIdx.x;
  const int blk  = blockIdx.x;
  const int wave = tid >> 6;
  const int lane = tid & 63;
  const int ln   = lane & 15;
  const int quad = lane >> 4;

  const int mbase = (blk >> 6) * 64;     // phase1/3 m-range
  const int bn    = blk & 63;
  const int n0g1  = bn * 16;             // phase1 n-cols
  const int n0g3  = bn * 32;             // phase3 n-cols

  // ---- preload persistent weight slices into LDS ----
  for (int i = tid; i < 1024; i += 256){          // Wc1: 16 rows x 64 granules
    int r = i >> 6, g = i & 63;
    short8 v = *(const short8*)(p.Wc1 + (size_t)(n0g1 + r)*512 + g*8);
    *(short8*)&W1s[r*520 + g*8] = v;
  }
  for (int i = tid; i < 5120; i += 256){          // Wc3: 32 rows x 160 granules
    int r = i / 160, g = i - r*160;
    short8 v = *(const short8*)(p.Wc3 + (size_t)(n0g3 + r)*1280 + g*8);
    *(short8*)&W3s[r*1288 + g*8] = v;
  }
  const float bv1  = p.bc1[n0g1 + ln];
  const float bv30 = p.bc3[n0g3 + ln];
  const float bv31 = p.bc3[n0g3 + 16 + ln];
  __syncthreads();

  int ep = 0;
  for (int t = 0; t <= 255; ++t){
    // ---------- phase 1: K1 GEMM (dec_att / gate / preds(t-1)), A = h ----------
    if (p.dl[mbase] >= t){
      const int m0 = mbase + wave*16;
      const u16* ap = p.h_bf + (size_t)(m0 + ln)*512 + quad*8;
      f32x4 a1 = {0.f,0.f,0.f,0.f};
      short8 acur = *(const short8*)ap;
      #pragma unroll
      for (int kt = 0; kt < 16; ++kt){
        short8 anext;
        if (kt < 15) anext = *(const short8*)(ap + (kt+1)*32);
        short8 b = *(const short8*)&W1s[ln*520 + kt*32 + quad*8];
        a1 = __builtin_amdgcn_mfma_f32_16x16x32_bf16(acur, b, a1, 0, 0, 0);
        acur = anext;
      }
      const int n = n0g1 + ln;
      #pragma unroll
      for (int r2 = 0; r2 < 4; ++r2){
        int gm = m0 + quad*4 + r2;
        float v = a1[r2] + bv1;
        if (n < 256)      p.dec_att[gm*256 + n] = v;
        else if (n < 768) p.gatev[gm*512 + (n-256)] = sigf(v);
        else if (n < 961){
          int tp = t - 1;
          if (tp >= 0 && tp < p.dl[gm])
            p.preds[((size_t)gm*255 + tp)*193 + (n-768)] = v;
        }
      }
    }
    if (t == 255) break;
    gridbar(p.bar, ep, blk); ++ep;

    // ---------- phase 2: attention for batch element blk ----------
    if (t < p.dl[blk]){
      float* da  = scr;
      float* wfs = scr + 256;
      float* al  = scr + 512;
      float* red = scr + 768;
      da[tid]  = p.dec_att[blk*256 + tid];
      wfs[tid] = p.wfull[tid];
      __syncthreads();
      float s = -1e30f;
      if (tid < 196){
        s = p.bfull[0];
        const u16* row = p.enc_att + ((size_t)blk*196 + tid)*256;
        #pragma unroll 4
        for (int i = 0; i < 32; ++i){
          short8 v = *(const short8*)(row + i*8);
          const float* dd = &da[i*8];
          const float* ww = &wfs[i*8];
          #pragma unroll
          for (int j = 0; j < 8; ++j)
            s += fmaxf(bf2f((u16)v[j]) + dd[j], 0.f) * ww[j];
        }
      }
      float mx = s;
      for (int o = 32; o > 0; o >>= 1) mx = fmaxf(mx, __shfl_down(mx, o, 64));
      const int wid = tid >> 6;
      if (lane == 0) red[wid] = mx;
      __syncthreads();
      if (tid == 0) red[4] = fmaxf(fmaxf(red[0], red[1]), fmaxf(red[2], red[3]));
      __syncthreads();
      mx = red[4];
      float e = (tid < 196) ? expf(s - mx) : 0.f;
      float sm = e;
      for (int o = 32; o > 0; o >>= 1) sm += __shfl_down(sm, o, 64);
      if (lane == 0) red[wid] = sm;
      __syncthreads();
      if (tid == 0) red[5] = red[0] + red[1] + red[2] + red[3];
      __syncthreads();
      const float inv = 1.f / red[5];
      al[tid] = e * inv;
      __syncthreads();
      if (tid < 196)
        p.alphas[((size_t)blk*255 + t)*196 + tid] = al[tid];
      const u16* eb = p.enc_sb + (size_t)blk*100352;
      const int cc = 2*tid;
      float v0 = 0.f, v1 = 0.f;
      #pragma unroll 4
      for (int pp = 0; pp < 196; ++pp){
        u32 u = *(const u32*)&eb[(size_t)pp*512 + cc];
        float a = al[pp];
        v0 += a * bf2f((u16)(u & 0xffffu));
        v1 += a * bf2f((u16)(u >> 16));
      }
      u16* zb = p.z_bf + (size_t)blk*1280;
      zb[256 + cc]     = f2bf(p.gatev[blk*512 + cc]     * v0);
      zb[256 + cc + 1] = f2bf(p.gatev[blk*512 + cc + 1] * v1);
      int tok = p.caps_s[blk*256 + t];
      zb[tid] = p.emb_bf[tok*256 + tid];
      *(u32*)&zb[768 + cc] = *(const u32*)&p.h_bf[blk*512 + cc];
    }
    gridbar(p.bar, ep, blk); ++ep;

    // ---------- phase 3: K3 GEMM + fused LSTM, A = z ----------
    if (p.dl[mbase] > t){
      float* Cs = scr;   // 64 x 36 f32
      const int m0 = mbase + wave*16;
      const u16* ap = p.z_bf + (size_t)(m0 + ln)*1280 + quad*8;
      f32x4 c0 = {0.f,0.f,0.f,0.f}, c1 = {0.f,0.f,0.f,0.f};
      short8 acur = *(const short8*)ap;
      #pragma unroll 4
      for (int kt = 0; kt < 40; ++kt){
        short8 anext;
        if (kt < 39) anext = *(const short8*)(ap + (kt+1)*32);
        short8 b0 = *(const short8*)&W3s[ln*1288 + kt*32 + quad*8];
        short8 b1 = *(const short8*)&W3s[(16+ln)*1288 + kt*32 + quad*8];
        c0 = __builtin_amdgcn_mfma_f32_16x16x32_bf16(acur, b0, c0, 0, 0, 0);
        c1 = __builtin_amdgcn_mfma_f32_16x16x32_bf16(acur, b1, c1, 0, 0, 0);
        acur = anext;
      }
      #pragma unroll
      for (int r2 = 0; r2 < 4; ++r2){
        Cs[(wave*16 + quad*4 + r2)*36 + ln]      = c0[r2] + bv30;
        Cs[(wave*16 + quad*4 + r2)*36 + 16 + ln] = c1[r2] + bv31;
      }
      __syncthreads();
      #pragma unroll
      for (int r2 = 0; r2 < 2; ++r2){
        int idx = r2*256 + tid;
        int m = idx >> 3, ju = idx & 7;
        float4 g4 = *(const float4*)&Cs[m*36 + ju*4];
        int gm = mbase + m;
        int gj = (blk & 63)*8 + ju;
        if (t < p.dl[gm]){
          float ig = sigf(g4.x), fg = sigf(g4.y);
          float gg = tanhf(g4.z), og = sigf(g4.w);
          float cn = fg * p.c[gm*512 + gj] + ig * gg;
          float hn = og * tanhf(cn);
          p.c[gm*512 + gj] = cn;
          p.h_bf[gm*512 + gj] = f2bf(hn);
        }
      }
    }
    gridbar(p.bar, ep, blk); ++ep;
  }
}

extern "C" void kernel_launch(void* const* d_in, const int* in_sizes, int n_in,
                              void* d_out, int out_size, void* d_ws, size_t ws_size,
                              hipStream_t stream){
  (void)in_sizes; (void)n_in; (void)out_size; (void)ws_size;
  const float* enc   = (const float*)d_in[0];
  const int*   caps  = (const int*)d_in[1];
  const int*   clens = (const int*)d_in[2];
  const float* Wenc  = (const float*)d_in[3];
  const float* benc  = (const float*)d_in[4];
  const float* Wdec  = (const float*)d_in[5];
  const float* bdec  = (const float*)d_in[6];
  const float* Wfull = (const float*)d_in[7];
  const float* bfull = (const float*)d_in[8];
  const float* emb   = (const float*)d_in[9];
  const float* Wfc   = (const float*)d_in[10];
  const float* bfc   = (const float*)d_in[11];
  const float* Wih   = (const float*)d_in[12];
  const float* bih   = (const float*)d_in[13];
  const float* Whh   = (const float*)d_in[14];
  const float* bhh   = (const float*)d_in[15];
  const float* Winh  = (const float*)d_in[16];
  const float* binh  = (const float*)d_in[17];
  const float* Winc  = (const float*)d_in[18];
  const float* binc  = (const float*)d_in[19];
  const float* Wfb   = (const float*)d_in[20];
  const float* bfb   = (const float*)d_in[21];

  float* out       = (float*)d_out;
  float* out_preds = out;                  // 256*255*193
  float* out_caps  = out + 12599040;       // 256*256
  float* out_dl    = out + 12664576;       // 256
  float* out_alph  = out + 12664832;       // 256*255*196
  float* out_si    = out + 25459712;       // 256

  char* w = (char*)d_ws;
  size_t off = 0;
  auto alloc = [&](size_t bytes) -> void* {
    void* pp = w + off; off += (bytes + 255) & ~(size_t)255; return pp;
  };
  int*   si      = (int*)  alloc(256*4);
  int*   dlw     = (int*)  alloc(256*4);
  int*   bar     = (int*)  alloc(32*4);
  int*   caps_s  = (int*)  alloc(65536*4);
  float* c       = (float*)alloc(131072*4);
  float* dec_att = (float*)alloc(65536*4);
  float* gatev   = (float*)alloc(131072*4);
  float* bc0     = (float*)alloc(1024*4);
  float* bc1     = (float*)alloc(1024*4);
  float* bc3     = (float*)alloc(2048*4);
  u16*   mean_bf = (u16*)  alloc(131072*2);
  u16*   h_bf    = (u16*)  alloc(131072*2);
  u16*   z_bf    = (u16*)  alloc(327680*2);
  u16*   Wc0     = (u16*)  alloc(524288*2);
  u16*   Wc1     = (u16*)  alloc(524288*2);
  u16*   Wc3     = (u16*)  alloc(2621440*2);
  u16*   Wenc_bf = (u16*)  alloc(131072*2);
  u16*   emb_bf  = (u16*)  alloc(49408*2);
  u16*   enc_sb  = (u16*)  alloc(25690112ull*2);   // 256 x 196 x 512 bf16
  u16*   enc_att = (u16*)  alloc(12845056ull*2);   // 50176 x 256 bf16

  k_zero<<<1024, 256, 0, stream>>>(out_preds, 12599040/4, out_alph, 12794880/4, bar);
  k_sort<<<1, 256, 0, stream>>>(clens, si, dlw, out_dl, out_si);
  k_caps<<<256, 256, 0, stream>>>(caps, si, caps_s, out_caps);
  k_prep<<<256, 256, 0, stream>>>(enc, si, enc_sb);
  k_mean<<<256, 256, 0, stream>>>(enc, si, mean_bf);
  ConcatP cp{Wdec,bdec,Wfb,bfb,Wfc,bfc,Wih,bih,Whh,bhh,Winh,binh,Winc,binc,Wenc,emb,
             Wc0,Wc1,Wc3,Wenc_bf,emb_bf,bc0,bc1,bc3};
  k_concat<<<2048, 256, 0, stream>>>(cp);

  { // h0 / c0 : M=256, N=1024, K=512
    MfmaP g{};
    g.A = mean_bf; g.Bw = Wc0; g.bias = bc0; g.K = 512; g.N = 1024;
    g.h_bf = h_bf; g.c = c;
    k_mfma<1,1><<<dim3(16,4), 256, 0, stream>>>(g);
  }
  { // enc_att : M=50176, N=256, K=512, bf16 out
    MfmaP g{};
    g.A = enc_sb; g.Bw = Wenc_bf; g.bias = benc; g.K = 512; g.N = 256;
    g.out_bf = enc_att;
    k_mfma<0,2><<<dim3(2,784), 256, 0, stream>>>(g);
  }

  // persistent recurrence: 256 blocks (1/CU, forced by 108 KB LDS), 765 grid barriers
  StepP sp{};
  sp.Wc1 = Wc1; sp.Wc3 = Wc3; sp.bc1 = bc1; sp.bc3 = bc3;
  sp.enc_att = enc_att; sp.enc_sb = enc_sb; sp.emb_bf = emb_bf;
  sp.wfull = Wfull; sp.bfull = bfull;
  sp.caps_s = caps_s; sp.dl = dlw;
  sp.h_bf = h_bf; sp.z_bf = z_bf;
  sp.c = c; sp.dec_att = dec_att; sp.gatev = gatev;
  sp.preds = out_preds; sp.alphas = out_alph;
  sp.bar = bar;
  k_step<<<256, 256, 0, stream>>>(sp);
}

// Round 5
// 22550.317 us; speedup vs baseline: 3.0680x; 3.0680x over previous
//
#include <hip/hip_runtime.h>
#include <cstdint>
#include <cstddef>

// B=256, P=196, C=512, D=512, A=256, E=256, V=193, TC=256, T=255

typedef unsigned short u16;
typedef unsigned int u32;
typedef __attribute__((ext_vector_type(8))) short short8;
typedef __attribute__((ext_vector_type(4))) float f32x4;

__device__ __forceinline__ float sigf(float x){ return 1.f/(1.f+expf(-x)); }
__device__ __forceinline__ u16 f2bf(float f){
  u32 u = __builtin_bit_cast(u32, f);
  u32 r = (u + 0x7fffu + ((u>>16)&1u)) >> 16;
  return (u16)r;
}
__device__ __forceinline__ float bf2f(u16 u){
  u32 x = ((u32)u) << 16;
  return __builtin_bit_cast(float, x);
}

// ---------------- zero preds/alphas + barrier state ----------------
__global__ void k_zero(float* a, int na4, float* b, int nb4, int* bar){
  int i = blockIdx.x*blockDim.x + threadIdx.x;
  int stride = gridDim.x*blockDim.x;
  float4 z = make_float4(0.f,0.f,0.f,0.f);
  for (int j = i; j < na4; j += stride) ((float4*)a)[j] = z;
  for (int j = i; j < nb4; j += stride) ((float4*)b)[j] = z;
  if (blockIdx.x == 0 && threadIdx.x < 32) bar[threadIdx.x] = 0;
}

// ---------------- sort (stable descending by length) ----------------
__global__ void k_sort(const int* cap_lens, int* si, int* dlw, float* out_dl, float* out_si){
  __shared__ int lens[256];
  int tid = threadIdx.x;
  lens[tid] = cap_lens[tid];
  __syncthreads();
  int L = lens[tid];
  int rank = 0;
  for (int j = 0; j < 256; ++j){
    int Lj = lens[j];
    rank += ((Lj > L) || (Lj == L && j < tid)) ? 1 : 0;
  }
  si[rank] = tid;
  dlw[rank] = L - 1;
  out_dl[rank] = (float)(L - 1);
  out_si[rank] = (float)tid;
}

// ---------------- caps gather ----------------
__global__ void k_caps(const int* caps, const int* si, int* caps_s, float* out_caps){
  int b = blockIdx.x, t = threadIdx.x;
  int v = caps[si[b]*256 + t];
  caps_s[b*256 + t] = v;
  out_caps[b*256 + t] = (float)v;
}

// ---------------- gather+convert encoder rows to bf16 (sorted order) ----------------
__global__ void k_prep(const float* enc, const int* si, u16* enc_sb){
  int b = blockIdx.x, tid = threadIdx.x;
  const float* src = enc + (size_t)si[b]*100352;
  u16* dst = enc_sb + (size_t)b*100352;
  for (int i = tid; i < 25088; i += 256){
    float4 v = *(const float4*)&src[i*4];
    ushort4 o;
    o.x = f2bf(v.x); o.y = f2bf(v.y); o.z = f2bf(v.z); o.w = f2bf(v.w);
    *(ushort4*)&dst[i*4] = o;
  }
}

// ---------------- mean of encoder rows ----------------
__global__ void k_mean(const float* enc, const int* si, u16* mean_bf){
  int b = blockIdx.x, tid = threadIdx.x;
  const float* eb = enc + (size_t)si[b]*100352;
  int cc = 2*tid;
  float s0 = 0.f, s1 = 0.f;
  #pragma unroll 4
  for (int pp = 0; pp < 196; ++pp){
    float2 v = *(const float2*)&eb[(size_t)pp*512 + cc];
    s0 += v.x; s1 += v.y;
  }
  mean_bf[b*512 + cc]     = f2bf(s0 * (1.f/196.f));
  mean_bf[b*512 + cc + 1] = f2bf(s1 * (1.f/196.f));
}

// ---------------- weight concat + bf16 convert ----------------
struct ConcatP {
  const float *Wdec,*bdec,*Wfb,*bfb,*Wfc,*bfc,*Wih,*bih,*Whh,*bhh,*Winh,*binh,*Winc,*binc,*Wenc,*emb;
  u16 *Wc0,*Wc1,*Wc3,*Wenc_bf,*emb_bf;
  float *bc0,*bc1,*bc3;
};
__global__ void k_concat(ConcatP p){
  int idx = blockIdx.x*blockDim.x + threadIdx.x;
  int stride = gridDim.x*blockDim.x;
  for (int i = idx; i < 1024*512; i += stride){
    int n = i >> 9, k = i & 511;
    float v = (n < 512) ? p.Winh[n*512 + k] : p.Winc[(n-512)*512 + k];
    p.Wc0[i] = f2bf(v);
  }
  for (int i = idx; i < 1024; i += stride)
    p.bc0[i] = (i < 512) ? p.binh[i] : p.binc[i-512];
  for (int i = idx; i < 1024*512; i += stride){
    int n = i >> 9, k = i & 511;
    float v = (n < 256) ? p.Wdec[n*512+k]
            : (n < 768) ? p.Wfb[(n-256)*512+k]
            : (n < 961) ? p.Wfc[(n-768)*512+k] : 0.f;
    p.Wc1[i] = f2bf(v);
  }
  for (int i = idx; i < 1024; i += stride)
    p.bc1[i] = (i < 256) ? p.bdec[i] : (i < 768) ? p.bfb[i-256] : (i < 961) ? p.bfc[i-768] : 0.f;
  // Wc3: gate-interleaved [W_ih | W_hh] (2048 x 1280), row n'=4*j+g -> orig row g*512+j
  for (int i = idx; i < 2048*1280; i += stride){
    int n = i / 1280, k = i - n*1280;
    int j = n >> 2, g = n & 3, orow = g*512 + j;
    float v = (k < 768) ? p.Wih[orow*768 + k] : p.Whh[orow*512 + (k - 768)];
    p.Wc3[i] = f2bf(v);
  }
  for (int i = idx; i < 2048; i += stride){
    int j = i >> 2, g = i & 3, orow = g*512 + j;
    p.bc3[i] = p.bih[orow] + p.bhh[orow];
  }
  for (int i = idx; i < 256*512; i += stride) p.Wenc_bf[i] = f2bf(p.Wenc[i]);
  for (int i = idx; i < 193*256; i += stride) p.emb_bf[i] = f2bf(p.emb[i]);
}

// ---------------- setup MFMA GEMM (double-buffered), used for init + enc_att ----------------
struct MfmaP {
  const u16* A; const u16* Bw; const float* bias;
  int K, N;
  u16* out_bf;
  u16* h_bf; float* c;
};

template<int MODE, int NT>
__global__ __launch_bounds__(256) void k_mfma(MfmaP p){
  __shared__ __align__(16) unsigned char smem[16384 + 16384*NT];
  u16* As0 = (u16*)smem;
  u16* Bs0 = (u16*)(smem + 16384);

  const int tid  = threadIdx.x;
  const int bn0  = blockIdx.x * 64 * NT;
  const int bm0  = blockIdx.y * 64;
  const int wave = tid >> 6;
  const int lane = tid & 63;
  const int ln   = lane & 15;
  const int quad = lane >> 4;

  f32x4 acc[4][NT] = {};
  short8 pa[2], pb[2*NT];

  const int srow = tid >> 3;
  const int sgc  = tid & 7;

  #pragma unroll
  for (int r = 0; r < 2; ++r)
    pa[r] = *(const short8*)(p.A + (size_t)(bm0 + srow + 32*r)*p.K + sgc*8);
  #pragma unroll
  for (int r = 0; r < 2*NT; ++r)
    pb[r] = *(const short8*)(p.Bw + (size_t)(bn0 + srow + 32*r)*p.K + sgc*8);
  #pragma unroll
  for (int r = 0; r < 2; ++r){
    int row = srow + 32*r;
    *(short8*)&As0[row*64 + ((sgc ^ (row & 7))<<3)] = pa[r];
  }
  #pragma unroll
  for (int r = 0; r < 2*NT; ++r){
    int row = srow + 32*r;
    *(short8*)&Bs0[row*64 + ((sgc ^ (row & 7))<<3)] = pb[r];
  }

  const int nIter = p.K >> 6;
  int ib = 0;
  for (int it = 0; ; ){
    __syncthreads();
    const bool more = (it + 1 < nIter);
    if (more){
      int k0 = (it + 1) << 6;
      #pragma unroll
      for (int r = 0; r < 2; ++r)
        pa[r] = *(const short8*)(p.A + (size_t)(bm0 + srow + 32*r)*p.K + k0 + sgc*8);
      #pragma unroll
      for (int r = 0; r < 2*NT; ++r)
        pb[r] = *(const short8*)(p.Bw + (size_t)(bn0 + srow + 32*r)*p.K + k0 + sgc*8);
    }
    const u16* As = &As0[ib*4096];
    const u16* Bs = &Bs0[ib*4096*NT];
    #pragma unroll
    for (int kk = 0; kk < 2; ++kk){
      short8 af[4], bfr[NT];
      #pragma unroll
      for (int mt = 0; mt < 4; ++mt){
        int row = mt*16 + ln;
        int g = kk*4 + quad;
        af[mt] = *(const short8*)&As[row*64 + ((g ^ (row & 7))<<3)];
      }
      #pragma unroll
      for (int nt = 0; nt < NT; ++nt){
        int row = (wave*NT + nt)*16 + ln;
        int g = kk*4 + quad;
        bfr[nt] = *(const short8*)&Bs[row*64 + ((g ^ (row & 7))<<3)];
      }
      #pragma unroll
      for (int mt = 0; mt < 4; ++mt)
        #pragma unroll
        for (int nt = 0; nt < NT; ++nt)
          acc[mt][nt] = __builtin_amdgcn_mfma_f32_16x16x32_bf16(af[mt], bfr[nt], acc[mt][nt], 0, 0, 0);
    }
    if (!more) break;
    ib ^= 1;
    u16* Aw = &As0[ib*4096];
    u16* Bww = &Bs0[ib*4096*NT];
    #pragma unroll
    for (int r = 0; r < 2; ++r){
      int row = srow + 32*r;
      *(short8*)&Aw[row*64 + ((sgc ^ (row & 7))<<3)] = pa[r];
    }
    #pragma unroll
    for (int r = 0; r < 2*NT; ++r){
      int row = srow + 32*r;
      *(short8*)&Bww[row*64 + ((sgc ^ (row & 7))<<3)] = pb[r];
    }
    ++it;
  }

  #pragma unroll
  for (int nt = 0; nt < NT; ++nt){
    int n = bn0 + (wave*NT + nt)*16 + ln;
    float bv = p.bias[n];
    #pragma unroll
    for (int mt = 0; mt < 4; ++mt)
      #pragma unroll
      for (int r = 0; r < 4; ++r){
        int m = bm0 + mt*16 + quad*4 + r;
        float v = acc[mt][nt][r] + bv;
        if (MODE == 0){
          p.out_bf[(size_t)m*p.N + n] = f2bf(v);
        } else { // MODE 1
          if (n < 512) p.h_bf[m*512 + n] = f2bf(v);
          else         p.c[m*512 + n - 512] = v;
        }
      }
  }
}

// ---------------- grid barrier: relaxed arrive/poll, ONE wb + ONE inv per block ----------------
// The round-4 version polled with ACQUIRE (cache-wide buffer_inv per poll iteration):
// 255 spinning blocks invalidated every XCD L2 ~every µs -> 4.6 GB HBM refetch, 79 GB/s crawl.
// Fix: fences OUTSIDE the poll loop; relaxed atomics (LLC coherence point, no cache ops);
// acquire-load fallback every 64 polls as deadlock insurance.
__device__ __forceinline__ void gridbar(int* bar, int ep, int blk){
  __syncthreads();
  if (threadIdx.x == 0){
    __threadfence();   // release: flush this XCD L2 to LLC (once)
    int g = blk & 15;
    int v = __hip_atomic_fetch_add(&bar[g], 1, __ATOMIC_RELAXED, __HIP_MEMORY_SCOPE_AGENT);
    if ((v & 15) == 15){
      int r = __hip_atomic_fetch_add(&bar[16], 1, __ATOMIC_RELAXED, __HIP_MEMORY_SCOPE_AGENT);
      if ((r & 15) == 15)
        __hip_atomic_store(&bar[17], ep + 1, __ATOMIC_RELAXED, __HIP_MEMORY_SCOPE_AGENT);
    }
    int spins = 0;
    while (true){
      int f = (++spins & 63)
            ? __hip_atomic_load(&bar[17], __ATOMIC_RELAXED, __HIP_MEMORY_SCOPE_AGENT)
            : __hip_atomic_load(&bar[17], __ATOMIC_ACQUIRE, __HIP_MEMORY_SCOPE_AGENT);
      if (f > ep) break;
      __builtin_amdgcn_s_sleep(4);
    }
    __threadfence();   // acquire: invalidate stale local caches (once)
  }
  __syncthreads();
}

// ---------------- persistent step kernel: 256 blocks x 256 threads, 1 block/CU ----------------
struct StepP {
  const u16 *Wc1, *Wc3;
  const float *bc1, *bc3;
  const u16 *enc_att, *enc_sb, *emb_bf;
  const float *wfull, *bfull;
  const int *caps_s, *dl;
  u16 *h_bf, *z_bf;
  float *c, *dec_att, *gatev, *preds, *alphas;
  int* bar;
};

__global__ __launch_bounds__(256) void k_step(StepP p){
  __shared__ __align__(16) unsigned char smem[111616];
  u16* W1s = (u16*)smem;                     // 16 x 520 bf16  (16640 B)
  u16* W3s = (u16*)(smem + 16640);           // 32 x 1288 bf16 (82432 B) -> ends 99072
  float* wfs = (float*)(smem + 99072);       // 256 f32 persistent (1024 B) -> 100096
  float* scr = (float*)(smem + 100096);      // 11520 B scratch overlay

  const int tid  = threadIdx.x;
  const int blk  = blockIdx.x;
  const int wave = tid >> 6;
  const int lane = tid & 63;
  const int ln   = lane & 15;
  const int quad = lane >> 4;

  const int mbase = (blk >> 6) * 64;
  const int bn    = blk & 63;
  const int n0g1  = bn * 16;
  const int n0g3  = bn * 32;

  // ---- preload persistent weight slices + wfull into LDS ----
  for (int i = tid; i < 1024; i += 256){
    int r = i >> 6, g = i & 63;
    short8 v = *(const short8*)(p.Wc1 + (size_t)(n0g1 + r)*512 + g*8);
    *(short8*)&W1s[r*520 + g*8] = v;
  }
  for (int i = tid; i < 5120; i += 256){
    int r = i / 160, g = i - r*160;
    short8 v = *(const short8*)(p.Wc3 + (size_t)(n0g3 + r)*1280 + g*8);
    *(short8*)&W3s[r*1288 + g*8] = v;
  }
  wfs[tid] = p.wfull[tid];
  const float bf0  = p.bfull[0];
  const float bv1  = p.bc1[n0g1 + ln];
  const float bv30 = p.bc3[n0g3 + ln];
  const float bv31 = p.bc3[n0g3 + 16 + ln];
  __syncthreads();

  int ep = 0;
  for (int t = 0; t <= 255; ++t){
    // ---------- phase 1: K1 GEMM (dec_att / gate / preds(t-1)), A = h ----------
    if (p.dl[mbase] >= t){
      const int m0 = mbase + wave*16;
      const u16* ap = p.h_bf + (size_t)(m0 + ln)*512 + quad*8;
      f32x4 a1 = {0.f,0.f,0.f,0.f};
      short8 acur = *(const short8*)ap;
      #pragma unroll
      for (int kt = 0; kt < 16; ++kt){
        short8 anext;
        if (kt < 15) anext = *(const short8*)(ap + (kt+1)*32);
        short8 b = *(const short8*)&W1s[ln*520 + kt*32 + quad*8];
        a1 = __builtin_amdgcn_mfma_f32_16x16x32_bf16(acur, b, a1, 0, 0, 0);
        acur = anext;
      }
      const int n = n0g1 + ln;
      #pragma unroll
      for (int r2 = 0; r2 < 4; ++r2){
        int gm = m0 + quad*4 + r2;
        float v = a1[r2] + bv1;
        if (n < 256)      p.dec_att[gm*256 + n] = v;
        else if (n < 768) p.gatev[gm*512 + (n-256)] = sigf(v);
        else if (n < 961){
          int tp = t - 1;
          if (tp >= 0 && tp < p.dl[gm])
            p.preds[((size_t)gm*255 + tp)*193 + (n-768)] = v;
        }
      }
    }
    if (t == 255) break;
    gridbar(p.bar, ep, blk); ++ep;

    // ---------- phase 2: attention for batch element blk ----------
    if (t < p.dl[blk]){
      float* da  = scr;
      float* al  = scr + 256;
      float* red = scr + 512;
      da[tid] = p.dec_att[blk*256 + tid];
      __syncthreads();
      float s = -1e30f;
      if (tid < 196){
        s = bf0;
        const u16* row = p.enc_att + ((size_t)blk*196 + tid)*256;
        #pragma unroll 4
        for (int i = 0; i < 32; ++i){
          short8 v = *(const short8*)(row + i*8);
          const float* dd = &da[i*8];
          const float* ww = &wfs[i*8];
          #pragma unroll
          for (int j = 0; j < 8; ++j)
            s += fmaxf(bf2f((u16)v[j]) + dd[j], 0.f) * ww[j];
        }
      }
      float mx = s;
      for (int o = 32; o > 0; o >>= 1) mx = fmaxf(mx, __shfl_down(mx, o, 64));
      const int wid = tid >> 6;
      if (lane == 0) red[wid] = mx;
      __syncthreads();
      if (tid == 0) red[4] = fmaxf(fmaxf(red[0], red[1]), fmaxf(red[2], red[3]));
      __syncthreads();
      mx = red[4];
      float e = (tid < 196) ? expf(s - mx) : 0.f;
      float sm = e;
      for (int o = 32; o > 0; o >>= 1) sm += __shfl_down(sm, o, 64);
      if (lane == 0) red[wid] = sm;
      __syncthreads();
      if (tid == 0) red[5] = red[0] + red[1] + red[2] + red[3];
      __syncthreads();
      const float inv = 1.f / red[5];
      al[tid] = e * inv;
      __syncthreads();
      if (tid < 196)
        p.alphas[((size_t)blk*255 + t)*196 + tid] = al[tid];
      const u16* eb = p.enc_sb + (size_t)blk*100352;
      const int cc = 2*tid;
      float v0 = 0.f, v1 = 0.f;
      #pragma unroll 4
      for (int pp = 0; pp < 196; ++pp){
        u32 u = *(const u32*)&eb[(size_t)pp*512 + cc];
        float a = al[pp];
        v0 += a * bf2f((u16)(u & 0xffffu));
        v1 += a * bf2f((u16)(u >> 16));
      }
      u16* zb = p.z_bf + (size_t)blk*1280;
      zb[256 + cc]     = f2bf(p.gatev[blk*512 + cc]     * v0);
      zb[256 + cc + 1] = f2bf(p.gatev[blk*512 + cc + 1] * v1);
      int tok = p.caps_s[blk*256 + t];
      zb[tid] = p.emb_bf[tok*256 + tid];
      *(u32*)&zb[768 + cc] = *(const u32*)&p.h_bf[blk*512 + cc];
    }
    gridbar(p.bar, ep, blk); ++ep;

    // ---------- phase 3: K3 GEMM + fused LSTM, A = z ----------
    if (p.dl[mbase] > t){
      float* Cs = scr;   // 64 x 36 f32
      const int m0 = mbase + wave*16;
      const u16* ap = p.z_bf + (size_t)(m0 + ln)*1280 + quad*8;
      f32x4 c0 = {0.f,0.f,0.f,0.f}, c1 = {0.f,0.f,0.f,0.f};
      short8 acur = *(const short8*)ap;
      #pragma unroll 4
      for (int kt = 0; kt < 40; ++kt){
        short8 anext;
        if (kt < 39) anext = *(const short8*)(ap + (kt+1)*32);
        short8 b0 = *(const short8*)&W3s[ln*1288 + kt*32 + quad*8];
        short8 b1 = *(const short8*)&W3s[(16+ln)*1288 + kt*32 + quad*8];
        c0 = __builtin_amdgcn_mfma_f32_16x16x32_bf16(acur, b0, c0, 0, 0, 0);
        c1 = __builtin_amdgcn_mfma_f32_16x16x32_bf16(acur, b1, c1, 0, 0, 0);
        acur = anext;
      }
      #pragma unroll
      for (int r2 = 0; r2 < 4; ++r2){
        Cs[(wave*16 + quad*4 + r2)*36 + ln]      = c0[r2] + bv30;
        Cs[(wave*16 + quad*4 + r2)*36 + 16 + ln] = c1[r2] + bv31;
      }
      __syncthreads();
      #pragma unroll
      for (int r2 = 0; r2 < 2; ++r2){
        int idx = r2*256 + tid;
        int m = idx >> 3, ju = idx & 7;
        float4 g4 = *(const float4*)&Cs[m*36 + ju*4];
        int gm = mbase + m;
        int gj = (blk & 63)*8 + ju;
        if (t < p.dl[gm]){
          float ig = sigf(g4.x), fg = sigf(g4.y);
          float gg = tanhf(g4.z), og = sigf(g4.w);
          float cn = fg * p.c[gm*512 + gj] + ig * gg;
          float hn = og * tanhf(cn);
          p.c[gm*512 + gj] = cn;
          p.h_bf[gm*512 + gj] = f2bf(hn);
        }
      }
    }
    gridbar(p.bar, ep, blk); ++ep;
  }
}

extern "C" void kernel_launch(void* const* d_in, const int* in_sizes, int n_in,
                              void* d_out, int out_size, void* d_ws, size_t ws_size,
                              hipStream_t stream){
  (void)in_sizes; (void)n_in; (void)out_size; (void)ws_size;
  const float* enc   = (const float*)d_in[0];
  const int*   caps  = (const int*)d_in[1];
  const int*   clens = (const int*)d_in[2];
  const float* Wenc  = (const float*)d_in[3];
  const float* benc  = (const float*)d_in[4];
  const float* Wdec  = (const float*)d_in[5];
  const float* bdec  = (const float*)d_in[6];
  const float* Wfull = (const float*)d_in[7];
  const float* bfull = (const float*)d_in[8];
  const float* emb   = (const float*)d_in[9];
  const float* Wfc   = (const float*)d_in[10];
  const float* bfc   = (const float*)d_in[11];
  const float* Wih   = (const float*)d_in[12];
  const float* bih   = (const float*)d_in[13];
  const float* Whh   = (const float*)d_in[14];
  const float* bhh   = (const float*)d_in[15];
  const float* Winh  = (const float*)d_in[16];
  const float* binh  = (const float*)d_in[17];
  const float* Winc  = (const float*)d_in[18];
  const float* binc  = (const float*)d_in[19];
  const float* Wfb   = (const float*)d_in[20];
  const float* bfb   = (const float*)d_in[21];

  float* out       = (float*)d_out;
  float* out_preds = out;                  // 256*255*193
  float* out_caps  = out + 12599040;       // 256*256
  float* out_dl    = out + 12664576;       // 256
  float* out_alph  = out + 12664832;       // 256*255*196
  float* out_si    = out + 25459712;       // 256

  char* w = (char*)d_ws;
  size_t off = 0;
  auto alloc = [&](size_t bytes) -> void* {
    void* pp = w + off; off += (bytes + 255) & ~(size_t)255; return pp;
  };
  int*   si      = (int*)  alloc(256*4);
  int*   dlw     = (int*)  alloc(256*4);
  int*   bar     = (int*)  alloc(32*4);
  int*   caps_s  = (int*)  alloc(65536*4);
  float* c       = (float*)alloc(131072*4);
  float* dec_att = (float*)alloc(65536*4);
  float* gatev   = (float*)alloc(131072*4);
  float* bc0     = (float*)alloc(1024*4);
  float* bc1     = (float*)alloc(1024*4);
  float* bc3     = (float*)alloc(2048*4);
  u16*   mean_bf = (u16*)  alloc(131072*2);
  u16*   h_bf    = (u16*)  alloc(131072*2);
  u16*   z_bf    = (u16*)  alloc(327680*2);
  u16*   Wc0     = (u16*)  alloc(524288*2);
  u16*   Wc1     = (u16*)  alloc(524288*2);
  u16*   Wc3     = (u16*)  alloc(2621440*2);
  u16*   Wenc_bf = (u16*)  alloc(131072*2);
  u16*   emb_bf  = (u16*)  alloc(49408*2);
  u16*   enc_sb  = (u16*)  alloc(25690112ull*2);   // 256 x 196 x 512 bf16
  u16*   enc_att = (u16*)  alloc(12845056ull*2);   // 50176 x 256 bf16

  k_zero<<<1024, 256, 0, stream>>>(out_preds, 12599040/4, out_alph, 12794880/4, bar);
  k_sort<<<1, 256, 0, stream>>>(clens, si, dlw, out_dl, out_si);
  k_caps<<<256, 256, 0, stream>>>(caps, si, caps_s, out_caps);
  k_prep<<<256, 256, 0, stream>>>(enc, si, enc_sb);
  k_mean<<<256, 256, 0, stream>>>(enc, si, mean_bf);
  ConcatP cp{Wdec,bdec,Wfb,bfb,Wfc,bfc,Wih,bih,Whh,bhh,Winh,binh,Winc,binc,Wenc,emb,
             Wc0,Wc1,Wc3,Wenc_bf,emb_bf,bc0,bc1,bc3};
  k_concat<<<2048, 256, 0, stream>>>(cp);

  { // h0 / c0 : M=256, N=1024, K=512
    MfmaP g{};
    g.A = mean_bf; g.Bw = Wc0; g.bias = bc0; g.K = 512; g.N = 1024;
    g.h_bf = h_bf; g.c = c;
    k_mfma<1,1><<<dim3(16,4), 256, 0, stream>>>(g);
  }
  { // enc_att : M=50176, N=256, K=512, bf16 out
    MfmaP g{};
    g.A = enc_sb; g.Bw = Wenc_bf; g.bias = benc; g.K = 512; g.N = 256;
    g.out_bf = enc_att;
    k_mfma<0,2><<<dim3(2,784), 256, 0, stream>>>(g);
  }

  // persistent recurrence: 256 blocks (1/CU, forced by 109 KB LDS), 765 grid barriers
  StepP sp{};
  sp.Wc1 = Wc1; sp.Wc3 = Wc3; sp.bc1 = bc1; sp.bc3 = bc3;
  sp.enc_att = enc_att; sp.enc_sb = enc_sb; sp.emb_bf = emb_bf;
  sp.wfull = Wfull; sp.bfull = bfull;
  sp.caps_s = caps_s; sp.dl = dlw;
  sp.h_bf = h_bf; sp.z_bf = z_bf;
  sp.c = c; sp.dec_att = dec_att; sp.gatev = gatev;
  sp.preds = out_preds; sp.alphas = out_alph;
  sp.bar = bar;
  k_step<<<256, 256, 0, stream>>>(sp);
}